// Round 5
// baseline (162.658 us; speedup 1.0000x reference)
//
#include <hip/hip_runtime.h>
#include <math.h>

#define B_ROWS 8192
#define NU 512
#define FEATS 64
#define RPB 8      // rows per block (= waves per block)
#define TOPK_K 8

typedef unsigned long long ull;
typedef unsigned short ushort8 __attribute__((ext_vector_type(8)));

// xor-1 / xor-2 lane exchange via DPP quad_perm (VALU pipe, no DS)
template <int CTRL>
__device__ __forceinline__ ull dpp_u64(ull x) {
  int lo = (int)(unsigned)(x & 0xffffffffULL);
  int hi = (int)(unsigned)(x >> 32);
  lo = __builtin_amdgcn_update_dpp(lo, lo, CTRL, 0xf, 0xf, true);
  hi = __builtin_amdgcn_update_dpp(hi, hi, CTRL, 0xf, 0xf, true);
  return ((ull)(unsigned)hi << 32) | (ull)(unsigned)lo;
}

__device__ __forceinline__ ull bperm_u64(int addr, ull x) {
  int lo = (int)(unsigned)(x & 0xffffffffULL);
  int hi = (int)(unsigned)(x >> 32);
  lo = __builtin_amdgcn_ds_bpermute(addr, lo);
  hi = __builtin_amdgcn_ds_bpermute(addr, hi);
  return ((ull)(unsigned)hi << 32) | (ull)(unsigned)lo;
}

// compare-exchange: after call, (a,b) ordered ascending iff asc
__device__ __forceinline__ void ce(ull& a, ull& b, bool asc) {
  const bool lt = a < b;
  const bool sw = (lt != asc);
  const ull t = sw ? b : a;
  b = sw ? a : b;
  a = t;
}

// cross-lane pass: lane-xor M, merge-size direction bit KB = K>>3
template <unsigned M, unsigned KB>
__device__ __forceinline__ void cross_t(ull v[8], unsigned lane, int addr) {
  const bool asc = ((lane & KB) == 0u);
  const bool takeMin = (((lane & M) == 0u) == asc);
#pragma unroll
  for (int i = 0; i < 8; ++i) {
    ull o;
    if constexpr (M == 1)      o = dpp_u64<0xB1>(v[i]);   // quad_perm [1,0,3,2]
    else if constexpr (M == 2) o = dpp_u64<0x4E>(v[i]);   // quad_perm [2,3,0,1]
    else                       o = bperm_u64(addr, v[i]);
    const bool keep = ((v[i] < o) == takeMin);
    v[i] = keep ? v[i] : o;
  }
}

// one bitonic merge stage of size K (16..512), fully compile-time unrolled
template <unsigned K>
__device__ __forceinline__ void stage_t(ull v[8], unsigned lane,
                                        int a4, int a8, int a16, int a32) {
  constexpr unsigned KB = (K >> 3);
  if constexpr (K >= 512) cross_t<32, KB>(v, lane, a32);
  if constexpr (K >= 256) cross_t<16, KB>(v, lane, a16);
  if constexpr (K >= 128) cross_t<8,  KB>(v, lane, a8);
  if constexpr (K >= 64)  cross_t<4,  KB>(v, lane, a4);
  if constexpr (K >= 32)  cross_t<2,  KB>(v, lane, 0);
  cross_t<1, KB>(v, lane, 0);
  const bool asc = ((lane & KB) == 0u);
  ce(v[0], v[4], asc); ce(v[1], v[5], asc); ce(v[2], v[6], asc); ce(v[3], v[7], asc);
  ce(v[0], v[2], asc); ce(v[1], v[3], asc); ce(v[4], v[6], asc); ce(v[5], v[7], asc);
  ce(v[0], v[1], asc); ce(v[2], v[3], asc); ce(v[4], v[5], asc); ce(v[6], v[7], asc);
}

// Register-budget note (r2/r3 evidence): 512-thread blocks get a ~48-64 VGPR
// budget on this target; exceeding it spills (r3: +30 MB HBM scratch traffic).
// The distance phase below is therefore tiled as quarter-column pairs over
// 4-row groups: peak live set ~56 regs, c loaded 32x/thread (vs 128 under
// per-row remat), each float4 of c pinned by a tiny asm so it cannot be
// rematerialized. Accumulation order and reduction tree are bit-identical
// to the XLA reference.
__global__ __launch_bounds__(512)
void lcm_kernel(const float* __restrict__ x, const float* __restrict__ c,
                float* __restrict__ out) {
#pragma clang fp contract(off)
  __shared__ ull keys[RPB * NU];                          // 32 KB
  __shared__ __align__(16) unsigned short rks[RPB * NU];  // 8 KB (40 KB total -> 4 blocks/CU)

  const int t = threadIdx.x;
  const int r0 = blockIdx.x * RPB;

  // ---- distances ----
  {
    const int n = t;
    const float4* c4 = (const float4*)c + (size_t)n * 16;
    float* o_d = out;

#pragma unroll
    for (int h = 0; h < 2; ++h) {
      float h8[4][4];  // s8[j], j=0..3, per row   (= rr[j] + rr[j+8])
      float g8[4][4];  // s8[4+j], j=0..3, per row (= rr[4+j] + rr[12+j])

      // ---- quarter-pair A: jq=0 (j=0..3) with jq=2 (j=8..11) ----
      {
        float rrA[4][4], rrB[4][4];
#pragma unroll
        for (int k = 0; k < 4; ++k) {
          float4 cA = c4[k * 4 + 0];
          asm volatile("" : "+v"(cA.x), "+v"(cA.y), "+v"(cA.z), "+v"(cA.w));
#pragma unroll
          for (int r = 0; r < 4; ++r) {
            const float* __restrict__ xr =
                x + (size_t)(r0 + h * 4 + r) * FEATS + 16 * k;  // block-uniform
            const float4 xv = *(const float4*)(xr + 0);
            const float t0 = xv.x - cA.x;
            const float t1 = xv.y - cA.y;
            const float t2 = xv.z - cA.z;
            const float t3 = xv.w - cA.w;
            if (k == 0) {
              rrA[r][0] = t0 * t0; rrA[r][1] = t1 * t1;
              rrA[r][2] = t2 * t2; rrA[r][3] = t3 * t3;
            } else {
              rrA[r][0] = rrA[r][0] + t0 * t0; rrA[r][1] = rrA[r][1] + t1 * t1;
              rrA[r][2] = rrA[r][2] + t2 * t2; rrA[r][3] = rrA[r][3] + t3 * t3;
            }
          }
          float4 cB = c4[k * 4 + 2];
          asm volatile("" : "+v"(cB.x), "+v"(cB.y), "+v"(cB.z), "+v"(cB.w));
#pragma unroll
          for (int r = 0; r < 4; ++r) {
            const float* __restrict__ xr =
                x + (size_t)(r0 + h * 4 + r) * FEATS + 16 * k;
            const float4 xv = *(const float4*)(xr + 8);
            const float t0 = xv.x - cB.x;
            const float t1 = xv.y - cB.y;
            const float t2 = xv.z - cB.z;
            const float t3 = xv.w - cB.w;
            if (k == 0) {
              rrB[r][0] = t0 * t0; rrB[r][1] = t1 * t1;
              rrB[r][2] = t2 * t2; rrB[r][3] = t3 * t3;
            } else {
              rrB[r][0] = rrB[r][0] + t0 * t0; rrB[r][1] = rrB[r][1] + t1 * t1;
              rrB[r][2] = rrB[r][2] + t2 * t2; rrB[r][3] = rrB[r][3] + t3 * t3;
            }
          }
        }
#pragma unroll
        for (int r = 0; r < 4; ++r) {
#pragma unroll
          for (int j = 0; j < 4; ++j) h8[r][j] = rrA[r][j] + rrB[r][j];
        }
      }

      // ---- quarter-pair B: jq=1 (j=4..7) with jq=3 (j=12..15) ----
      {
        float rrA[4][4], rrB[4][4];
#pragma unroll
        for (int k = 0; k < 4; ++k) {
          float4 cA = c4[k * 4 + 1];
          asm volatile("" : "+v"(cA.x), "+v"(cA.y), "+v"(cA.z), "+v"(cA.w));
#pragma unroll
          for (int r = 0; r < 4; ++r) {
            const float* __restrict__ xr =
                x + (size_t)(r0 + h * 4 + r) * FEATS + 16 * k;
            const float4 xv = *(const float4*)(xr + 4);
            const float t0 = xv.x - cA.x;
            const float t1 = xv.y - cA.y;
            const float t2 = xv.z - cA.z;
            const float t3 = xv.w - cA.w;
            if (k == 0) {
              rrA[r][0] = t0 * t0; rrA[r][1] = t1 * t1;
              rrA[r][2] = t2 * t2; rrA[r][3] = t3 * t3;
            } else {
              rrA[r][0] = rrA[r][0] + t0 * t0; rrA[r][1] = rrA[r][1] + t1 * t1;
              rrA[r][2] = rrA[r][2] + t2 * t2; rrA[r][3] = rrA[r][3] + t3 * t3;
            }
          }
          float4 cB = c4[k * 4 + 3];
          asm volatile("" : "+v"(cB.x), "+v"(cB.y), "+v"(cB.z), "+v"(cB.w));
#pragma unroll
          for (int r = 0; r < 4; ++r) {
            const float* __restrict__ xr =
                x + (size_t)(r0 + h * 4 + r) * FEATS + 16 * k;
            const float4 xv = *(const float4*)(xr + 12);
            const float t0 = xv.x - cB.x;
            const float t1 = xv.y - cB.y;
            const float t2 = xv.z - cB.z;
            const float t3 = xv.w - cB.w;
            if (k == 0) {
              rrB[r][0] = t0 * t0; rrB[r][1] = t1 * t1;
              rrB[r][2] = t2 * t2; rrB[r][3] = t3 * t3;
            } else {
              rrB[r][0] = rrB[r][0] + t0 * t0; rrB[r][1] = rrB[r][1] + t1 * t1;
              rrB[r][2] = rrB[r][2] + t2 * t2; rrB[r][3] = rrB[r][3] + t3 * t3;
            }
          }
        }
#pragma unroll
        for (int r = 0; r < 4; ++r) {
#pragma unroll
          for (int j = 0; j < 4; ++j) g8[r][j] = rrA[r][j] + rrB[r][j];
        }
      }

      // ---- per-row reduction tree (identical to reference order) ----
#pragma unroll
      for (int r = 0; r < 4; ++r) {
        float s4[4], s2[2];
#pragma unroll
        for (int j = 0; j < 4; ++j) s4[j] = h8[r][j] + g8[r][j];
        s2[0] = s4[0] + s4[2];
        s2[1] = s4[1] + s4[3];
        const float tot = s2[0] + s2[1];
        const float dv = (float)__builtin_sqrt((double)tot);
        o_d[(size_t)(r0 + h * 4 + r) * NU + n] = dv;
        keys[(h * 4 + r) * NU + n] = ((ull)__float_as_uint(dv) << 32) | (ull)n;
      }
    }
  }
  __syncthreads();

  // ---- per-wave stable bitonic sort of 512 keys (wave w = row w) ----
  {
    const unsigned lane = (unsigned)(t & 63);
    const int w = t >> 6;

    ull v[8];
#pragma unroll
    for (int i = 0; i < 8; ++i) v[i] = keys[w * NU + i * 64 + (int)lane];

    // pre-stages K=2,4,8 (directions compile-time / lane-bit0)
    ce(v[0], v[1], true);  ce(v[2], v[3], false);
    ce(v[4], v[5], true);  ce(v[6], v[7], false);            // K=2
    ce(v[0], v[2], true);  ce(v[1], v[3], true);
    ce(v[4], v[6], false); ce(v[5], v[7], false);            // K=4 S=2
    ce(v[0], v[1], true);  ce(v[2], v[3], true);
    ce(v[4], v[5], false); ce(v[6], v[7], false);            // K=4 S=1
    {
      const bool a8 = ((lane & 1u) == 0u);                   // K=8
      ce(v[0], v[4], a8); ce(v[1], v[5], a8); ce(v[2], v[6], a8); ce(v[3], v[7], a8);
      ce(v[0], v[2], a8); ce(v[1], v[3], a8); ce(v[4], v[6], a8); ce(v[5], v[7], a8);
      ce(v[0], v[1], a8); ce(v[2], v[3], a8); ce(v[4], v[5], a8); ce(v[6], v[7], a8);
    }

    const int ad4  = (int)((lane ^ 4u)  << 2);
    const int ad8  = (int)((lane ^ 8u)  << 2);
    const int ad16 = (int)((lane ^ 16u) << 2);
    const int ad32 = (int)((lane ^ 32u) << 2);
    stage_t<16>(v, lane, ad4, ad8, ad16, ad32);
    stage_t<32>(v, lane, ad4, ad8, ad16, ad32);
    stage_t<64>(v, lane, ad4, ad8, ad16, ad32);
    stage_t<128>(v, lane, ad4, ad8, ad16, ad32);
    stage_t<256>(v, lane, ad4, ad8, ad16, ad32);
    stage_t<512>(v, lane, ad4, ad8, ad16, ad32);

    const int row = r0 + w;
    float* o_is = out + (size_t)B_ROWS * NU;
    float* o_k  = o_is + (size_t)B_ROWS * NU;
    float* o_z  = o_k + (size_t)B_ROWS * NU;
    float* o_xc = o_z + (size_t)B_ROWS * NU;

    int idxv[8];
#pragma unroll
    for (int i = 0; i < 8; ++i) idxv[i] = (int)(v[i] & 0x1ffULL);

    // i_sort: coalesced float4 stores
    float4 fa, fb;
    fa.x = (float)idxv[0]; fa.y = (float)idxv[1];
    fa.z = (float)idxv[2]; fa.w = (float)idxv[3];
    fb.x = (float)idxv[4]; fb.y = (float)idxv[5];
    fb.z = (float)idxv[6]; fb.w = (float)idxv[7];
    float4* isrow = (float4*)(o_is + (size_t)row * NU);
    isrow[lane * 2 + 0] = fa;
    isrow[lane * 2 + 1] = fb;

    // ---- inverse permutation in LDS (wave-private row) ----
    // rank of original index idxv[i] is e = lane*8 + i
#pragma unroll
    for (int i = 0; i < 8; ++i)
      rks[w * NU + idxv[i]] = (unsigned short)((int)lane * 8 + i);

    // lane l (l<8) holds zval = 1/(l+1); recovered per-element via bpermute.
    // Constants fold identically to 1.0f/(float)(i+1) (IEEE round-to-nearest).
    const unsigned l8 = lane & 7u;
    const float v00 = (l8 & 1u) ? 0.5f : 1.0f;
    const float v01 = (l8 & 1u) ? 0.25f : (1.0f / 3.0f);
    const float v10 = (l8 & 1u) ? (1.0f / 6.0f) : 0.2f;
    const float v11 = (l8 & 1u) ? 0.125f : (1.0f / 7.0f);
    const float va  = (l8 & 2u) ? v01 : v00;
    const float vb  = (l8 & 2u) ? v11 : v10;
    const float zv  = (l8 & 4u) ? vb : va;
    const int zvb = __float_as_int(zv);

    // lane-contiguous rank read: 8 u16 = one ds_read_b128, then float4 stores
    const ushort8 ev = *(const ushort8*)(&rks[w * NU + (int)lane * 8]);
    int e[8];
#pragma unroll
    for (int i = 0; i < 8; ++i) e[i] = (int)ev[i];

    float4 k0, k1, z0, z1;
    k0.x = (float)e[0]; k0.y = (float)e[1]; k0.z = (float)e[2]; k0.w = (float)e[3];
    k1.x = (float)e[4]; k1.y = (float)e[5]; k1.z = (float)e[6]; k1.w = (float)e[7];
    float zt[8];
#pragma unroll
    for (int i = 0; i < 8; ++i) {
      const int zb = __builtin_amdgcn_ds_bpermute((e[i] & 63) << 2, zvb);
      zt[i] = (e[i] < TOPK_K) ? __int_as_float(zb) : 0.0f;
    }
    z0.x = zt[0]; z0.y = zt[1]; z0.z = zt[2]; z0.w = zt[3];
    z1.x = zt[4]; z1.y = zt[5]; z1.z = zt[6]; z1.w = zt[7];

    float4* krow = (float4*)(o_k + (size_t)row * NU + (size_t)lane * 8);
    float4* zrow = (float4*)(o_z + (size_t)row * NU + (size_t)lane * 8);
    krow[0] = k0; krow[1] = k1;
    zrow[0] = z0; zrow[1] = z1;

    int top = idxv[0];
    top = __shfl(top, 0, 64);
    o_xc[(size_t)row * FEATS + (int)lane] = c[top * FEATS + (int)lane];
  }
}

extern "C" void kernel_launch(void* const* d_in, const int* in_sizes, int n_in,
                              void* d_out, int out_size, void* d_ws, size_t ws_size,
                              hipStream_t stream) {
  const float* x = (const float*)d_in[0];
  const float* c = (const float*)d_in[1];
  float* out = (float*)d_out;
  lcm_kernel<<<dim3(B_ROWS / RPB), dim3(512), 0, stream>>>(x, c, out);
}

// Round 6
// 117.008 us; speedup vs baseline: 1.3901x; 1.3901x over previous
//
#include <hip/hip_runtime.h>
#include <math.h>

#define B_ROWS 8192
#define NU 512
#define FEATS 64
#define RPB 8      // rows per block (= waves per block)
#define TOPK_K 8

typedef unsigned long long ull;
typedef unsigned short ushort8 __attribute__((ext_vector_type(8)));
typedef float f32x2 __attribute__((ext_vector_type(2)));

// xor-1 / xor-2 lane exchange via DPP quad_perm (VALU pipe, no DS)
template <int CTRL>
__device__ __forceinline__ ull dpp_u64(ull x) {
  int lo = (int)(unsigned)(x & 0xffffffffULL);
  int hi = (int)(unsigned)(x >> 32);
  lo = __builtin_amdgcn_update_dpp(lo, lo, CTRL, 0xf, 0xf, true);
  hi = __builtin_amdgcn_update_dpp(hi, hi, CTRL, 0xf, 0xf, true);
  return ((ull)(unsigned)hi << 32) | (ull)(unsigned)lo;
}

__device__ __forceinline__ ull bperm_u64(int addr, ull x) {
  int lo = (int)(unsigned)(x & 0xffffffffULL);
  int hi = (int)(unsigned)(x >> 32);
  lo = __builtin_amdgcn_ds_bpermute(addr, lo);
  hi = __builtin_amdgcn_ds_bpermute(addr, hi);
  return ((ull)(unsigned)hi << 32) | (ull)(unsigned)lo;
}

// compare-exchange: after call, (a,b) ordered ascending iff asc
__device__ __forceinline__ void ce(ull& a, ull& b, bool asc) {
  const bool lt = a < b;
  const bool sw = (lt != asc);
  const ull t = sw ? b : a;
  b = sw ? a : b;
  a = t;
}

// cross-lane pass: lane-xor M, merge-size direction bit KB = K>>3
template <unsigned M, unsigned KB>
__device__ __forceinline__ void cross_t(ull v[8], unsigned lane, int addr) {
  const bool asc = ((lane & KB) == 0u);
  const bool takeMin = (((lane & M) == 0u) == asc);
#pragma unroll
  for (int i = 0; i < 8; ++i) {
    ull o;
    if constexpr (M == 1)      o = dpp_u64<0xB1>(v[i]);   // quad_perm [1,0,3,2]
    else if constexpr (M == 2) o = dpp_u64<0x4E>(v[i]);   // quad_perm [2,3,0,1]
    else                       o = bperm_u64(addr, v[i]);
    const bool keep = ((v[i] < o) == takeMin);
    v[i] = keep ? v[i] : o;
  }
}

// one bitonic merge stage of size K (16..512), fully compile-time unrolled
template <unsigned K>
__device__ __forceinline__ void stage_t(ull v[8], unsigned lane,
                                        int a4, int a8, int a16, int a32) {
  constexpr unsigned KB = (K >> 3);
  if constexpr (K >= 512) cross_t<32, KB>(v, lane, a32);
  if constexpr (K >= 256) cross_t<16, KB>(v, lane, a16);
  if constexpr (K >= 128) cross_t<8,  KB>(v, lane, a8);
  if constexpr (K >= 64)  cross_t<4,  KB>(v, lane, a4);
  if constexpr (K >= 32)  cross_t<2,  KB>(v, lane, 0);
  cross_t<1, KB>(v, lane, 0);
  const bool asc = ((lane & KB) == 0u);
  ce(v[0], v[4], asc); ce(v[1], v[5], asc); ce(v[2], v[6], asc); ce(v[3], v[7], asc);
  ce(v[0], v[2], asc); ce(v[1], v[3], asc); ce(v[4], v[6], asc); ce(v[5], v[7], asc);
  ce(v[0], v[1], asc); ce(v[2], v[3], asc); ce(v[4], v[5], asc); ce(v[6], v[7], asc);
}

// Lessons encoded (r2/r3/r5 counters): do NOT pin c in registers and do NOT
// grow the live set past the ~48-64 VGPR budget of 512-thread blocks.
// r1's remat'd c-loads are batched by the compiler and covered by 8 waves/SIMD
// (57 us); every residency "fix" lost (pins serialize VMEM: r5 = 104 us;
// bigger tiles spill: r3 = +30 MB scratch). The kernel is VALU-issue-bound,
// so this version packs the distance arithmetic into f32x2 so the backend can
// emit v_pk_add/mul_f32 (two IEEE f32 ops per instruction, per-element order
// unchanged -> bitwise-identical results).
__global__ __launch_bounds__(512)
void lcm_kernel(const float* __restrict__ x, const float* __restrict__ c,
                float* __restrict__ out) {
#pragma clang fp contract(off)
  __shared__ ull keys[RPB * NU];                          // 32 KB
  __shared__ __align__(16) unsigned short rks[RPB * NU];  // 8 KB (40 KB total -> 4 blocks/CU)

  const int t = threadIdx.x;
  const int r0 = blockIdx.x * RPB;

  // ---- distances: r1 structure, arithmetic packed as f32x2 pairs ----
  {
    const int n = t;
    float4 cs4[16];
    const float4* c4 = (const float4*)c + (size_t)n * 16;
#pragma unroll
    for (int q = 0; q < 16; ++q) cs4[q] = c4[q];

    float* o_d = out;
#pragma unroll
    for (int r = 0; r < RPB; ++r) {
      const float* __restrict__ xr = x + (size_t)(r0 + r) * FEATS;  // block-uniform
      // rr2[m] = (rr[2m], rr[2m+1]) of the reference's rr[16]
      f32x2 rr2[8];
#pragma unroll
      for (int k = 0; k < 4; ++k) {
        const float4 xq0 = *(const float4*)(xr + 16 * k + 0);
        const float4 xq1 = *(const float4*)(xr + 16 * k + 4);
        const float4 xq2 = *(const float4*)(xr + 16 * k + 8);
        const float4 xq3 = *(const float4*)(xr + 16 * k + 12);
        const float4 xq[4] = {xq0, xq1, xq2, xq3};
#pragma unroll
        for (int q = 0; q < 4; ++q) {
          const float4 cv = cs4[k * 4 + q];
          const float4 xv = xq[q];
          f32x2 xlo, xhi, clo, chi;
          xlo[0] = xv.x; xlo[1] = xv.y; xhi[0] = xv.z; xhi[1] = xv.w;
          clo[0] = cv.x; clo[1] = cv.y; chi[0] = cv.z; chi[1] = cv.w;
          const f32x2 dlo = xlo - clo;   // v_pk_add_f32 (neg)
          const f32x2 dhi = xhi - chi;
          if (k == 0) {
            rr2[q * 2 + 0] = dlo * dlo;                   // v_pk_mul_f32
            rr2[q * 2 + 1] = dhi * dhi;
          } else {
            rr2[q * 2 + 0] = rr2[q * 2 + 0] + dlo * dlo;  // mul then add (no fma)
            rr2[q * 2 + 1] = rr2[q * 2 + 1] + dhi * dhi;
          }
        }
      }
      // reduction tree, identical pairing to the reference:
      // s8[j] = rr[j] + rr[j+8]  -> s8_2[m] = rr2[m] + rr2[m+4]
      f32x2 s8_2[4], s4_2[2], s2_2;
#pragma unroll
      for (int m = 0; m < 4; ++m) s8_2[m] = rr2[m] + rr2[m + 4];
#pragma unroll
      for (int m = 0; m < 2; ++m) s4_2[m] = s8_2[m] + s8_2[m + 2];
      s2_2 = s4_2[0] + s4_2[1];          // = (s2[0], s2[1])
      const float tot = s2_2[0] + s2_2[1];
      const float dv = (float)__builtin_sqrt((double)tot);
      o_d[(size_t)(r0 + r) * NU + n] = dv;
      keys[r * NU + n] = ((ull)__float_as_uint(dv) << 32) | (ull)n;
    }
  }
  __syncthreads();

  // ---- per-wave stable bitonic sort of 512 keys (wave w = row w) ----
  {
    const unsigned lane = (unsigned)(t & 63);
    const int w = t >> 6;

    ull v[8];
#pragma unroll
    for (int i = 0; i < 8; ++i) v[i] = keys[w * NU + i * 64 + (int)lane];

    // pre-stages K=2,4,8 (directions compile-time / lane-bit0)
    ce(v[0], v[1], true);  ce(v[2], v[3], false);
    ce(v[4], v[5], true);  ce(v[6], v[7], false);            // K=2
    ce(v[0], v[2], true);  ce(v[1], v[3], true);
    ce(v[4], v[6], false); ce(v[5], v[7], false);            // K=4 S=2
    ce(v[0], v[1], true);  ce(v[2], v[3], true);
    ce(v[4], v[5], false); ce(v[6], v[7], false);            // K=4 S=1
    {
      const bool a8 = ((lane & 1u) == 0u);                   // K=8
      ce(v[0], v[4], a8); ce(v[1], v[5], a8); ce(v[2], v[6], a8); ce(v[3], v[7], a8);
      ce(v[0], v[2], a8); ce(v[1], v[3], a8); ce(v[4], v[6], a8); ce(v[5], v[7], a8);
      ce(v[0], v[1], a8); ce(v[2], v[3], a8); ce(v[4], v[5], a8); ce(v[6], v[7], a8);
    }

    const int ad4  = (int)((lane ^ 4u)  << 2);
    const int ad8  = (int)((lane ^ 8u)  << 2);
    const int ad16 = (int)((lane ^ 16u) << 2);
    const int ad32 = (int)((lane ^ 32u) << 2);
    stage_t<16>(v, lane, ad4, ad8, ad16, ad32);
    stage_t<32>(v, lane, ad4, ad8, ad16, ad32);
    stage_t<64>(v, lane, ad4, ad8, ad16, ad32);
    stage_t<128>(v, lane, ad4, ad8, ad16, ad32);
    stage_t<256>(v, lane, ad4, ad8, ad16, ad32);
    stage_t<512>(v, lane, ad4, ad8, ad16, ad32);

    const int row = r0 + w;
    float* o_is = out + (size_t)B_ROWS * NU;
    float* o_k  = o_is + (size_t)B_ROWS * NU;
    float* o_z  = o_k + (size_t)B_ROWS * NU;
    float* o_xc = o_z + (size_t)B_ROWS * NU;

    int idxv[8];
#pragma unroll
    for (int i = 0; i < 8; ++i) idxv[i] = (int)(v[i] & 0x1ffULL);

    // i_sort: coalesced float4 stores
    float4 fa, fb;
    fa.x = (float)idxv[0]; fa.y = (float)idxv[1];
    fa.z = (float)idxv[2]; fa.w = (float)idxv[3];
    fb.x = (float)idxv[4]; fb.y = (float)idxv[5];
    fb.z = (float)idxv[6]; fb.w = (float)idxv[7];
    float4* isrow = (float4*)(o_is + (size_t)row * NU);
    isrow[lane * 2 + 0] = fa;
    isrow[lane * 2 + 1] = fb;

    // ---- inverse permutation in LDS (wave-private row) ----
    // rank of original index idxv[i] is e = lane*8 + i
#pragma unroll
    for (int i = 0; i < 8; ++i)
      rks[w * NU + idxv[i]] = (unsigned short)((int)lane * 8 + i);

    // lane l (l<8) holds zval = 1/(l+1); recovered per-element via bpermute.
    // Constants fold identically to 1.0f/(float)(i+1) (IEEE round-to-nearest).
    const unsigned l8 = lane & 7u;
    const float v00 = (l8 & 1u) ? 0.5f : 1.0f;
    const float v01 = (l8 & 1u) ? 0.25f : (1.0f / 3.0f);
    const float v10 = (l8 & 1u) ? (1.0f / 6.0f) : 0.2f;
    const float v11 = (l8 & 1u) ? 0.125f : (1.0f / 7.0f);
    const float va  = (l8 & 2u) ? v01 : v00;
    const float vb  = (l8 & 2u) ? v11 : v10;
    const float zv  = (l8 & 4u) ? vb : va;
    const int zvb = __float_as_int(zv);

    // lane-contiguous rank read: 8 u16 = one ds_read_b128, then float4 stores
    const ushort8 ev = *(const ushort8*)(&rks[w * NU + (int)lane * 8]);
    int e[8];
#pragma unroll
    for (int i = 0; i < 8; ++i) e[i] = (int)ev[i];

    float4 k0, k1, z0, z1;
    k0.x = (float)e[0]; k0.y = (float)e[1]; k0.z = (float)e[2]; k0.w = (float)e[3];
    k1.x = (float)e[4]; k1.y = (float)e[5]; k1.z = (float)e[6]; k1.w = (float)e[7];
    float zt[8];
#pragma unroll
    for (int i = 0; i < 8; ++i) {
      const int zb = __builtin_amdgcn_ds_bpermute((e[i] & 63) << 2, zvb);
      zt[i] = (e[i] < TOPK_K) ? __int_as_float(zb) : 0.0f;
    }
    z0.x = zt[0]; z0.y = zt[1]; z0.z = zt[2]; z0.w = zt[3];
    z1.x = zt[4]; z1.y = zt[5]; z1.z = zt[6]; z1.w = zt[7];

    float4* krow = (float4*)(o_k + (size_t)row * NU + (size_t)lane * 8);
    float4* zrow = (float4*)(o_z + (size_t)row * NU + (size_t)lane * 8);
    krow[0] = k0; krow[1] = k1;
    zrow[0] = z0; zrow[1] = z1;

    int top = idxv[0];
    top = __shfl(top, 0, 64);
    o_xc[(size_t)row * FEATS + (int)lane] = c[top * FEATS + (int)lane];
  }
}

extern "C" void kernel_launch(void* const* d_in, const int* in_sizes, int n_in,
                              void* d_out, int out_size, void* d_ws, size_t ws_size,
                              hipStream_t stream) {
  const float* x = (const float*)d_in[0];
  const float* c = (const float*)d_in[1];
  float* out = (float*)d_out;
  lcm_kernel<<<dim3(B_ROWS / RPB), dim3(512), 0, stream>>>(x, c, out);
}